// Round 8
// baseline (265.004 us; speedup 1.0000x reference)
//
#include <hip/hip_runtime.h>
#include <hip/hip_bf16.h>

// out = base + (base @ A2.T) @ bb.T  where A2 = M.T @ A, M = B.T @ diag(e) @ aa.T  (16x16)
// base [N=16384 rows][D=4096], A[16][4096], E[32], B[32][16], aa[16][32], bb[4096][16]
// Fused, 512-thread blocks (8 waves), ROWS=32, LDS 66 KiB -> 2 blocks/CU so
// co-resident blocks overlap phase A (HBM reads) with phase B (writes + L3 reads).
// Phase A: lane = (row = lane&31, k-half = lane>>5); swizzled LDS staging;
//   A2t via 2-address-broadcast vector loads (L1/L2 resident).
// Phase B: R5's known-good form: 4 cols/thread, bbr[4][4], t via LDS broadcast,
//   f32x4 NT stores; 2 windows of 2048 cols.

#define D_DIM 4096
#define K_LR 16
#define R_LR 32
#define ROWS 32        // rows per block
#define NW 8           // waves per block (512 threads)
#define WWIN 512       // per-wave col window in phase A
#define DC 64          // cols staged per chunk ([32 rows][64 cols] = 8 KiB/wave)
#define NCH (WWIN / DC)    // 8 chunks
#define BWIN 2048      // phase-B window (512 threads * 4 cols)

typedef float f32x4 __attribute__((ext_vector_type(4)));

__global__ void __launch_bounds__(256) prep_kernel(const float* __restrict__ A,
                                                   const float* __restrict__ E,
                                                   const float* __restrict__ Bm,
                                                   const float* __restrict__ aa,
                                                   float* __restrict__ A2t) {
    __shared__ float Ms[K_LR][K_LR];
    const int t = threadIdx.x;
    {
        const int k = t >> 4, kp = t & 15;
        float s = 0.f;
        #pragma unroll
        for (int r = 0; r < R_LR; ++r)
            s += Bm[r * K_LR + k] * E[r] * aa[kp * R_LR + r];
        Ms[k][kp] = s;  // M[k][k'] = sum_r B[r][k] * e[r] * aa[k'][r]
    }
    __syncthreads();
    const int d = blockIdx.x * 256 + t;
    float acc[K_LR];
    #pragma unroll
    for (int kp = 0; kp < K_LR; ++kp) acc[kp] = 0.f;
    #pragma unroll
    for (int k = 0; k < K_LR; ++k) {
        const float a = A[k * D_DIM + d];
        #pragma unroll
        for (int kp = 0; kp < K_LR; ++kp) acc[kp] = fmaf(a, Ms[k][kp], acc[kp]);
    }
    #pragma unroll
    for (int kq = 0; kq < 4; ++kq) {
        f32x4 v = { acc[kq*4+0], acc[kq*4+1], acc[kq*4+2], acc[kq*4+3] };
        *(f32x4*)(A2t + (size_t)d * K_LR + kq * 4) = v;  // A2t[d][k'] d-major
    }
}

union ShA {
    float stage[NW][ROWS][DC];   // 64 KiB, per-wave 8 KiB quadrants (phase A)
    float tred[NW][ROWS][K_LR];  // 16 KiB wave partials (after barrier)
};

__global__ void __launch_bounds__(512, 4) fused_kernel(const float* __restrict__ base,
                                                       const float* __restrict__ A2t,
                                                       const float* __restrict__ bb,
                                                       float* __restrict__ out, int N) {
    __shared__ ShA sh;
    __shared__ float tfin[ROWS][K_LR];        // 2 KiB final t
    const int tid  = threadIdx.x;
    const int lane = tid & 63;
    const int wv   = __builtin_amdgcn_readfirstlane(tid >> 6);
    const int r0   = blockIdx.x * ROWS;

    // ---------------- Phase A: t = rows @ A2t (barrier-free per wave) -------
    {
        const int c4 = lane & 15;           // 16B slot for staging
        const int rg = lane >> 4;           // row offset within 4-row group
        const int row = lane & 31;          // compute row
        const int kh  = lane >> 5;          // k-half (0: k0..7, 1: k8..15)
        const int rmask = row & 15;
        const int d0 = wv * WWIN;
        char* wbase = (char*)&sh.stage[wv][0][0];

        f32x4 acc0 = {0.f, 0.f, 0.f, 0.f};
        f32x4 acc1 = {0.f, 0.f, 0.f, 0.f};

        f32x4 st[8];
        #pragma unroll
        for (int i = 0; i < 8; ++i)
            st[i] = *(const f32x4*)(base + (size_t)(r0 + i*4 + rg) * D_DIM + d0 + c4*4);

        for (int c = 0; c < NCH; ++c) {
            // stage chunk c (swizzled: slot = c4 ^ (row&15), conflict-free)
            #pragma unroll
            for (int i = 0; i < 8; ++i) {
                const int wr = i*4 + rg;
                *(f32x4*)(wbase + wr * 256 + ((c4 ^ (wr & 15)) << 4)) = st[i];
            }
            // prefetch chunk c+1 (overlaps with compute below)
            if (c + 1 < NCH) {
                const int dcn = d0 + (c + 1) * DC;
                #pragma unroll
                for (int i = 0; i < 8; ++i)
                    st[i] = *(const f32x4*)(base + (size_t)(r0 + i*4 + rg) * D_DIM + dcn + c4*4);
            }
            // compute chunk c: lanes l and l+32 share row, split k-halves
            const int dc = d0 + c * DC;
            #pragma unroll
            for (int j = 0; j < 16; ++j) {
                const f32x4 b4 = *(const f32x4*)(wbase + row * 256 + ((j ^ rmask) << 4));
                #pragma unroll
                for (int jj = 0; jj < 4; ++jj) {
                    const float* ap = A2t + (size_t)(dc + j*4 + jj) * K_LR + kh * 8;
                    const f32x4 a0 = *(const f32x4*)(ap);      // k 0..3 of half
                    const f32x4 a1 = *(const f32x4*)(ap + 4);  // k 4..7 of half
                    acc0 += b4[jj] * a0;
                    acc1 += b4[jj] * a1;
                }
            }
        }
        __syncthreads();   // all waves done with their stage quadrant
        *(f32x4*)(&sh.tred[wv][row][kh * 8 + 0]) = acc0;
        *(f32x4*)(&sh.tred[wv][row][kh * 8 + 4]) = acc1;
    }
    __syncthreads();
    // reduce 8 wave partials -> tfin (512 threads: one (r,k) each)
    {
        const int r = tid >> 4, k = tid & 15;
        float s = 0.f;
        #pragma unroll
        for (int w = 0; w < NW; ++w)
            s += sh.tred[w][r][k];
        tfin[r][k] = s;
    }
    __syncthreads();

    // ---------------- Phase B: out = base + t @ bb.T (R5 known-good) --------
    #pragma unroll
    for (int win = 0; win < D_DIM / BWIN; ++win) {
        const int cbase = win * BWIN + tid * 4;   // this thread's 4 cols
        f32x4 bbr[4][4];
        #pragma unroll
        for (int q = 0; q < 4; ++q)
            #pragma unroll
            for (int kq = 0; kq < 4; ++kq)
                bbr[q][kq] = *(const f32x4*)(bb + (size_t)(cbase + q) * K_LR + kq * 4);

        #pragma unroll 2
        for (int r = 0; r < ROWS; ++r) {
            f32x4 t16[4];
            #pragma unroll
            for (int kq = 0; kq < 4; ++kq)
                t16[kq] = *(const f32x4*)(&tfin[r][kq * 4]);  // uniform broadcast

            const size_t row = (size_t)(r0 + r);
            const f32x4 bv = *(const f32x4*)(base + row * D_DIM + cbase);
            f32x4 ov;
            #pragma unroll
            for (int q = 0; q < 4; ++q) {
                float o = bv[q];
                #pragma unroll
                for (int k = 0; k < K_LR; ++k)
                    o = fmaf(t16[k >> 2][k & 3], bbr[q][k >> 2][k & 3], o);
                ov[q] = o;
            }
            __builtin_nontemporal_store(ov, (f32x4*)(out + row * D_DIM + cbase));
        }
    }
}

extern "C" void kernel_launch(void* const* d_in, const int* in_sizes, int n_in,
                              void* d_out, int out_size, void* d_ws, size_t ws_size,
                              hipStream_t stream) {
    const float* base = (const float*)d_in[0];
    const float* A    = (const float*)d_in[1];
    const float* E    = (const float*)d_in[2];
    const float* Bm   = (const float*)d_in[3];
    const float* aa   = (const float*)d_in[4];
    const float* bb   = (const float*)d_in[5];
    float* out = (float*)d_out;
    const int N = in_sizes[0] / D_DIM;  // 16384 rows

    float* A2t = (float*)d_ws;          // 256 KiB

    prep_kernel<<<D_DIM / 256, 256, 0, stream>>>(A, E, Bm, aa, A2t);
    fused_kernel<<<N / ROWS, 512, 0, stream>>>(base, A2t, bb, out, N);
}

// Round 9
// 168.521 us; speedup vs baseline: 1.5725x; 1.5725x over previous
//
#include <hip/hip_runtime.h>
#include <hip/hip_bf16.h>

// out = base + (base @ A2.T) @ bb.T  where A2 = M.T @ A, M = B.T @ diag(e) @ aa.T  (16x16)
// base [N=16384 rows][D=4096], A[16][4096], E[32], B[32][16], aa[16][32], bb[4096][16]
// 3-kernel split (phase visibility + per-kernel occupancy):
//  k1: Tp[16][N][16] partials, barrier-free, 4 blk/CU, lane=row, s_load A2t.
//  k1b: reduce partials -> T[N][16].
//  k2: out = base + T @ bb.T; T via wave-uniform s_load (ZERO LDS), bbr in regs,
//      rolling base prefetch, NT stores, 4 blk/CU.

#define D_DIM 4096
#define K_LR 16
#define R_LR 32
#define ROWS 64       // rows per block tile
#define DC 32         // d-chunk staged in LDS per wave (128 B per row)
#define NSPLIT 4      // d-splits across blocks (k1)
#define DWIN 1024     // per-block d window
#define WWIN 256      // per-wave d window
#define NCH (WWIN / DC)   // 8 chunks
#define NPART 16      // NSPLIT * 4 waves partials

typedef float f32x4 __attribute__((ext_vector_type(4)));

__global__ void __launch_bounds__(256) prep_kernel(const float* __restrict__ A,
                                                   const float* __restrict__ E,
                                                   const float* __restrict__ Bm,
                                                   const float* __restrict__ aa,
                                                   float* __restrict__ A2t) {
    __shared__ float Ms[K_LR][K_LR];
    const int t = threadIdx.x;
    {
        const int k = t >> 4, kp = t & 15;
        float s = 0.f;
        #pragma unroll
        for (int r = 0; r < R_LR; ++r)
            s += Bm[r * K_LR + k] * E[r] * aa[kp * R_LR + r];
        Ms[k][kp] = s;  // M[k][k'] = sum_r B[r][k] * e[r] * aa[k'][r]
    }
    __syncthreads();
    const int d = blockIdx.x * 256 + t;
    float acc[K_LR];
    #pragma unroll
    for (int kp = 0; kp < K_LR; ++kp) acc[kp] = 0.f;
    #pragma unroll
    for (int k = 0; k < K_LR; ++k) {
        const float a = A[k * D_DIM + d];
        #pragma unroll
        for (int kp = 0; kp < K_LR; ++kp) acc[kp] = fmaf(a, Ms[k][kp], acc[kp]);
    }
    #pragma unroll
    for (int kq = 0; kq < 4; ++kq) {
        f32x4 v = { acc[kq*4+0], acc[kq*4+1], acc[kq*4+2], acc[kq*4+3] };
        *(f32x4*)(A2t + (size_t)d * K_LR + kq * 4) = v;  // A2t[d][k'] d-major
    }
}

// k1: Tp[wave_split][row][16] = sum over wave's 256-col window of base[row][d]*A2t[d][k]
// Barrier-free: stage[] is wave-private; XOR-swizzled LDS, reg-staged prefetch.
__global__ void __launch_bounds__(256, 8) k1_kernel(const float* __restrict__ base,
                                                    const float* __restrict__ A2t,
                                                    float* __restrict__ Tp, int N) {
    __shared__ float stage[4][ROWS][DC];  // 32 KiB, per-wave 8 KiB quadrants
    const int tid  = threadIdx.x;
    const int lane = tid & 63;
    const int wv   = __builtin_amdgcn_readfirstlane(tid >> 6);
    const int a    = lane >> 3;          // row-within-8-group for staging
    const int b    = lane & 7;           // col4-group for staging
    const int rowtile = blockIdx.x / NSPLIT;
    const int split   = blockIdx.x % NSPLIT;
    const int r0 = rowtile * ROWS;
    const int d0 = split * DWIN + wv * WWIN;

    char* wbase = (char*)&stage[wv][0][0];
    const int swz_w = 16 * (b ^ a);      // swizzled 16B slot for staging write
    const int swz_r = (lane & 7) << 4;   // read-side XOR (row = lane)

    float acc[K_LR];
    #pragma unroll
    for (int k = 0; k < K_LR; ++k) acc[k] = 0.f;

    f32x4 st[8];
    // prologue: load chunk 0 into regs
    #pragma unroll
    for (int i = 0; i < 8; ++i)
        st[i] = *(const f32x4*)(base + (size_t)(r0 + i*8 + a) * D_DIM + d0 + 4*b);

    for (int c = 0; c < NCH; ++c) {
        // stage chunk c: regs -> LDS (swizzled, conflict-free permutation)
        #pragma unroll
        for (int i = 0; i < 8; ++i)
            *(f32x4*)(wbase + (i*8 + a) * 128 + swz_w) = st[i];
        // prefetch chunk c+1 into regs (overlaps with compute below)
        if (c + 1 < NCH) {
            const int dcn = d0 + (c + 1) * DC;
            #pragma unroll
            for (int i = 0; i < 8; ++i)
                st[i] = *(const f32x4*)(base + (size_t)(r0 + i*8 + a) * D_DIM + dcn + 4*b);
        }
        // compute chunk c: lane = row; A2t via wave-uniform scalar loads
        const int dc = d0 + c * DC;
        #pragma unroll
        for (int j = 0; j < DC/4; ++j) {
            const f32x4 b4 = *(const f32x4*)(wbase + lane * 128 + ((16*j) ^ swz_r));
            const float* a2p = A2t + (size_t)(dc + 4*j) * K_LR;
            #pragma unroll
            for (int jj = 0; jj < 4; ++jj) {
                const float bv = b4[jj];
                #pragma unroll
                for (int k = 0; k < K_LR; ++k)
                    acc[k] = fmaf(bv, a2p[jj * K_LR + k], acc[k]);
            }
        }
    }
    // each wave writes its own partial; no cross-wave reduce, no barrier
    const int ws = split * 4 + wv;
    float* tp = Tp + ((size_t)ws * N + r0 + lane) * K_LR;
    #pragma unroll
    for (int kq = 0; kq < 4; ++kq) {
        f32x4 v = { acc[kq*4+0], acc[kq*4+1], acc[kq*4+2], acc[kq*4+3] };
        *(f32x4*)(tp + kq * 4) = v;
    }
}

// k1b: T[i] = sum of 16 partials
__global__ void __launch_bounds__(256) k1b_kernel(const float* __restrict__ Tp,
                                                  float* __restrict__ T, int N) {
    const int g = blockIdx.x * 256 + threadIdx.x;      // float4 index, < N*16/4
    const size_t stride = (size_t)N * K_LR / 4;
    const f32x4* tp4 = (const f32x4*)Tp;
    f32x4 s = tp4[g];
    #pragma unroll
    for (int ws = 1; ws < NPART; ++ws)
        s += tp4[ws * stride + g];
    ((f32x4*)T)[g] = s;
}

// k2: out[row][d] = base[row][d] + sum_k T[row][k]*bb[d][k]
// No LDS: thread=4 cols, bb window register-resident, T via wave-uniform s_loads,
// rolling base prefetch.
__global__ void __launch_bounds__(256, 4) k2_kernel(const float* __restrict__ base,
                                                    const float* __restrict__ bb,
                                                    const float* __restrict__ T,
                                                    float* __restrict__ out, int N) {
    const int tid  = threadIdx.x;
    const int rowtile = blockIdx.x >> 2;          // N/64 rowtiles
    const int dwin    = blockIdx.x & 3;           // 4 d-windows of 1024
    const int r0 = rowtile * ROWS;
    const int cbase = dwin * 1024 + tid * 4;      // this thread's 4 cols

    // bb[cbase..cbase+3][0..15] -> 64 VGPRs, read once per block
    f32x4 bbr[4][4];
    #pragma unroll
    for (int q = 0; q < 4; ++q)
        #pragma unroll
        for (int kq = 0; kq < 4; ++kq)
            bbr[q][kq] = *(const f32x4*)(bb + (size_t)(cbase + q) * K_LR + kq * 4);

    f32x4 bv = *(const f32x4*)(base + (size_t)r0 * D_DIM + cbase);
    #pragma unroll 2
    for (int r = 0; r < ROWS; ++r) {
        const size_t row = (size_t)(r0 + r);
        // rolling prefetch of next row's base segment (independent of t)
        f32x4 bnext;
        if (r + 1 < ROWS)
            bnext = *(const f32x4*)(base + (row + 1) * D_DIM + cbase);

        const float* tp = T + row * K_LR;          // wave-uniform -> s_load
        float t16[K_LR];
        #pragma unroll
        for (int k = 0; k < K_LR; ++k) t16[k] = tp[k];

        f32x4 ov;
        #pragma unroll
        for (int q = 0; q < 4; ++q) {
            float o = bv[q];
            #pragma unroll
            for (int k = 0; k < K_LR; ++k)
                o = fmaf(t16[k], bbr[q][k >> 2][k & 3], o);
            ov[q] = o;
        }
        __builtin_nontemporal_store(ov, (f32x4*)(out + row * D_DIM + cbase));
        bv = bnext;
    }
}

extern "C" void kernel_launch(void* const* d_in, const int* in_sizes, int n_in,
                              void* d_out, int out_size, void* d_ws, size_t ws_size,
                              hipStream_t stream) {
    const float* base = (const float*)d_in[0];
    const float* A    = (const float*)d_in[1];
    const float* E    = (const float*)d_in[2];
    const float* Bm   = (const float*)d_in[3];
    const float* aa   = (const float*)d_in[4];
    const float* bb   = (const float*)d_in[5];
    float* out = (float*)d_out;
    const int N = in_sizes[0] / D_DIM;  // 16384 rows

    float* A2t = (float*)d_ws;                                   // 256 KiB @ 0
    float* Tp  = (float*)((char*)d_ws + (1u << 20));             // 16 MiB @ 1 MiB
    float* T   = (float*)((char*)d_ws + (32u << 20));            // 1 MiB  @ 32 MiB

    prep_kernel<<<D_DIM / 256, 256, 0, stream>>>(A, E, Bm, aa, A2t);
    k1_kernel<<<(N / ROWS) * NSPLIT, 256, 0, stream>>>(base, A2t, Tp, N);
    k1b_kernel<<<(N * K_LR / 4) / 256, 256, 0, stream>>>(Tp, T, N);
    k2_kernel<<<(N / ROWS) * 4, 256, 0, stream>>>(base, bb, T, out, N);
}

// Round 10
// 151.916 us; speedup vs baseline: 1.7444x; 1.1093x over previous
//
#include <hip/hip_runtime.h>
#include <hip/hip_bf16.h>

// out = base + (base @ A2.T) @ bb.T  where A2 = M.T @ A, M = B.T @ diag(e) @ aa.T  (16x16)
// base [N=16384 rows][D=4096], A[16][4096], E[32], B[32][16], aa[16][32], bb[4096][16]
// Fused, 1024-thread blocks (16 waves), 1 block/CU (LDS-bound).
// Phase A: t[64][16] = rows @ A2t (lane=row, swizzled LDS staging, uniform s_loads).
// Phase B: out = base + t @ bb.T, 4 cols/thread, bbr register-resident.
// KEY: __launch_bounds__(1024,4) -> 128-VGPR budget. Without it the compiler
// targets 8 waves/SIMD (VGPR<=64, impossible here: LDS caps at 1 block/CU) and
// SINKS the 64-float bbr loads into the row loop -> 4 GiB of L2 bb re-reads.

#define D_DIM 4096
#define K_LR 16
#define R_LR 32
#define ROWS 64        // rows per block
#define NW 16          // waves per block (1024 threads)
#define WWIN 256       // per-wave col window in phase A
#define DC 32          // cols staged per chunk (128 B per row)
#define NCH (WWIN / DC)    // 8 chunks

typedef float f32x4 __attribute__((ext_vector_type(4)));

__global__ void __launch_bounds__(256) prep_kernel(const float* __restrict__ A,
                                                   const float* __restrict__ E,
                                                   const float* __restrict__ Bm,
                                                   const float* __restrict__ aa,
                                                   float* __restrict__ A2t) {
    __shared__ float Ms[K_LR][K_LR];
    const int t = threadIdx.x;
    {
        const int k = t >> 4, kp = t & 15;
        float s = 0.f;
        #pragma unroll
        for (int r = 0; r < R_LR; ++r)
            s += Bm[r * K_LR + k] * E[r] * aa[kp * R_LR + r];
        Ms[k][kp] = s;  // M[k][k'] = sum_r B[r][k] * e[r] * aa[k'][r]
    }
    __syncthreads();
    const int d = blockIdx.x * 256 + t;
    float acc[K_LR];
    #pragma unroll
    for (int kp = 0; kp < K_LR; ++kp) acc[kp] = 0.f;
    #pragma unroll
    for (int k = 0; k < K_LR; ++k) {
        const float a = A[k * D_DIM + d];
        #pragma unroll
        for (int kp = 0; kp < K_LR; ++kp) acc[kp] = fmaf(a, Ms[k][kp], acc[kp]);
    }
    #pragma unroll
    for (int kq = 0; kq < 4; ++kq) {
        f32x4 v = { acc[kq*4+0], acc[kq*4+1], acc[kq*4+2], acc[kq*4+3] };
        *(f32x4*)(A2t + (size_t)d * K_LR + kq * 4) = v;  // A2t[d][k'] d-major
    }
}

union ShA {
    float stage[NW][ROWS][DC];   // 128 KiB, per-wave 8 KiB quadrants (phase A)
    float tred[NW][ROWS][K_LR];  // 64 KiB wave partials (after barrier)
};

__global__ void __launch_bounds__(1024, 4) fused_kernel(const float* __restrict__ base,
                                                        const float* __restrict__ A2t,
                                                        const float* __restrict__ bb,
                                                        float* __restrict__ out, int N) {
    __shared__ ShA sh;
    __shared__ float tfin[ROWS][K_LR];        // 4 KiB final t
    const int tid  = threadIdx.x;
    const int lane = tid & 63;
    const int wv   = __builtin_amdgcn_readfirstlane(tid >> 6);
    const int r0   = blockIdx.x * ROWS;

    // ---------------- Phase A: t = rows @ A2t (barrier-free per wave) -------
    {
        const int a = lane >> 3;            // row-within-8-group for staging
        const int b = lane & 7;             // col4-group for staging
        const int d0 = wv * WWIN;
        char* wbase = (char*)&sh.stage[wv][0][0];
        const int swz_w = 16 * (b ^ a);     // swizzled 16B slot for staging write
        const int swz_r = (lane & 7) << 4;  // read-side XOR (row = lane)

        float acc[K_LR];
        #pragma unroll
        for (int k = 0; k < K_LR; ++k) acc[k] = 0.f;

        f32x4 st[8];
        #pragma unroll
        for (int i = 0; i < 8; ++i)
            st[i] = *(const f32x4*)(base + (size_t)(r0 + i*8 + a) * D_DIM + d0 + 4*b);

        for (int c = 0; c < NCH; ++c) {
            #pragma unroll
            for (int i = 0; i < 8; ++i)
                *(f32x4*)(wbase + (i*8 + a) * 128 + swz_w) = st[i];
            if (c + 1 < NCH) {
                const int dcn = d0 + (c + 1) * DC;
                #pragma unroll
                for (int i = 0; i < 8; ++i)
                    st[i] = *(const f32x4*)(base + (size_t)(r0 + i*8 + a) * D_DIM + dcn + 4*b);
            }
            const int dc = d0 + c * DC;
            #pragma unroll
            for (int j = 0; j < DC/4; ++j) {
                const f32x4 b4 = *(const f32x4*)(wbase + lane * 128 + ((16*j) ^ swz_r));
                const float* a2p = A2t + (size_t)(dc + 4*j) * K_LR;  // uniform -> s_load
                #pragma unroll
                for (int jj = 0; jj < 4; ++jj) {
                    const float bv = b4[jj];
                    #pragma unroll
                    for (int k = 0; k < K_LR; ++k)
                        acc[k] = fmaf(bv, a2p[jj * K_LR + k], acc[k]);
                }
            }
        }
        __syncthreads();   // all waves done reading their stage quadrant
        #pragma unroll
        for (int kq = 0; kq < 4; ++kq) {
            f32x4 v = { acc[kq*4+0], acc[kq*4+1], acc[kq*4+2], acc[kq*4+3] };
            *(f32x4*)(&sh.tred[wv][lane][kq * 4]) = v;
        }
    }
    __syncthreads();
    // reduce 16 wave partials -> tfin (1024 threads: one (r,k) each)
    {
        const int r = tid >> 4, k = tid & 15;
        float s = 0.f;
        #pragma unroll
        for (int w = 0; w < NW; ++w)
            s += sh.tred[w][r][k];
        tfin[r][k] = s;
    }
    __syncthreads();

    // ---------------- Phase B: out = base + t @ bb.T ------------------------
    {
        const int cbase = tid * 4;            // this thread's 4 cols (covers all 4096)
        const f32x4* __restrict__ bbp = (const f32x4*)(bb + (size_t)cbase * K_LR);
        f32x4 bbr[4][4];
        #pragma unroll
        for (int q = 0; q < 4; ++q)
            #pragma unroll
            for (int kq = 0; kq < 4; ++kq)
                bbr[q][kq] = bbp[q * 4 + kq];

        const float* __restrict__ bp = base + (size_t)r0 * D_DIM + cbase;
        float* __restrict__ op = out + (size_t)r0 * D_DIM + cbase;

        f32x4 bv = *(const f32x4*)(bp);
        #pragma unroll 2
        for (int r = 0; r < ROWS; ++r) {
            // rolling prefetch of next row's base segment (L3-resident re-read)
            f32x4 bn;
            if (r + 1 < ROWS)
                bn = *(const f32x4*)(bp + (size_t)(r + 1) * D_DIM);

            f32x4 t16[4];
            #pragma unroll
            for (int kq = 0; kq < 4; ++kq)
                t16[kq] = *(const f32x4*)(&tfin[r][kq * 4]);  // uniform broadcast

            f32x4 ov;
            #pragma unroll
            for (int q = 0; q < 4; ++q) {
                float o = bv[q];
                #pragma unroll
                for (int k = 0; k < K_LR; ++k)
                    o = fmaf(t16[k >> 2][k & 3], bbr[q][k >> 2][k & 3], o);
                ov[q] = o;
            }
            __builtin_nontemporal_store(ov, (f32x4*)(op + (size_t)r * D_DIM));
            bv = bn;
        }
    }
}

extern "C" void kernel_launch(void* const* d_in, const int* in_sizes, int n_in,
                              void* d_out, int out_size, void* d_ws, size_t ws_size,
                              hipStream_t stream) {
    const float* base = (const float*)d_in[0];
    const float* A    = (const float*)d_in[1];
    const float* E    = (const float*)d_in[2];
    const float* Bm   = (const float*)d_in[3];
    const float* aa   = (const float*)d_in[4];
    const float* bb   = (const float*)d_in[5];
    float* out = (float*)d_out;
    const int N = in_sizes[0] / D_DIM;  // 16384 rows

    float* A2t = (float*)d_ws;          // 256 KiB

    prep_kernel<<<D_DIM / 256, 256, 0, stream>>>(A, E, Bm, aa, A2t);
    fused_kernel<<<N / ROWS, 1024, 0, stream>>>(base, A2t, bb, out, N);
}